// Round 13
// baseline (153.291 us; speedup 1.0000x reference)
//
#include <hip/hip_runtime.h>
#include <stdint.h>

typedef _Float16 half8  __attribute__((ext_vector_type(8)));
typedef float    f32x4  __attribute__((ext_vector_type(4)));
typedef float    f32x16 __attribute__((ext_vector_type(16)));
typedef uint32_t u32x4  __attribute__((ext_vector_type(4)));

#define FIN  288
#define NOUT 64
#define LPB  3844            // 62*62
#define NBF  20736           // bfrag half8 slots (331,776 B)
#define NBAS (16*64*16*64*2) // basis half8 slots (33.5 MB), [b][h][u16][w64][half2]
#define NXR  (16*64*2*64*2)  // relu(x) half8 slots (4.2 MB), [b][h][u2][w64][half2]
#define PADS 16              // OOB-read pad

// legacy LDS (fallback path, byte-identical to the round-0 verified kernel)
#define SCL  200
#define LDSL (31*SCL + 2*64 + 64 + 8)

// R12 counters: FETCH 158 MB = basis x 1.5 (row-amp) x 3 (jj re-reads missing
// L2). R10-z2's 29.5 MB/workload worked because CU c hosted blocks (c,z=0)
// and (c,z=1) = IDENTICAL data, sharing all af fetches. This round: real-work
// nh-split with nh = bid0>>8 so blocks c and c+256 (same CU by round-robin)
// are the two N-halves of the same (b,hg): identical af reads, disjoint out.
// Block = 512 thr, 8 waves (4 rows x 2 K), wave N=32. Math = verified R12.

// ---------------- cubic B-spline basis: 8 slots, f16-packed ----------------
__device__ inline half8 bspline8(float xv) {
  float u = fmaf(xv, 2.5f, 5.5f);
  float fi = floorf(u);
  int i = (int)fi;
  float t = u - fi, s = 1.0f - t;
  float t2 = t * t, t3 = t2 * t;
  float s2 = s * s, s3 = s2 * s;
  float w3 = t3 * 0.16666667f;
  float w0 = s3 * 0.16666667f;
  float w1 = fmaf(0.5f, t3, -t2) + 0.66666667f;
  float w2 = fmaf(0.5f, s3, -s2) + 0.66666667f;
  uint32_t u01 = __builtin_bit_cast(uint32_t, __builtin_amdgcn_cvt_pkrtz(w0, w1));
  uint32_t u23 = __builtin_bit_cast(uint32_t, __builtin_amdgcn_cvt_pkrtz(w2, w3));
  uint64_t V = (uint64_t)u01 | ((uint64_t)u23 << 32);
  uint32_t vl = (uint32_t)(V << 16);
  u32x4 fr;
#pragma unroll
  for (int q = 0; q < 4; ++q) {
    int d = i - 2 * q;
    uint32_t rr = (uint32_t)(V >> ((48 - 16 * d) & 63));
    fr[q] = ((uint32_t)d <= 3u) ? rr : ((d == 4) ? vl : 0u);
  }
  return __builtin_bit_cast(half8, fr);
}

// -------- prep: basis + relu(x) f16 + weight B-fragments, all in ws --------
__global__ __launch_bounds__(256) void prep_all(const float* __restrict__ x,
                                                const float* __restrict__ bw,
                                                const float* __restrict__ sw,
                                                const float* __restrict__ sc,
                                                half8* __restrict__ ws) {
  int bid = blockIdx.x;
  if (bid < 8192) {
    // basis: thread t writes slot t (coalesced stores)
    int t = bid * 256 + threadIdx.x;        // 0..2097151
    int half = t & 1;
    int w    = (t >> 1) & 63;
    int u    = (t >> 7) & 15;
    int bh   = t >> 11;                     // b*64 + h
    float xv = x[(size_t)(bh >> 6) * 131072 + (u * 2 + half) * 4096 +
                 (bh & 63) * 64 + w];
    ws[NBF + t] = bspline8(xv);
  } else if (bid < 9216) {
    // relu(x) -> f16: slot ((bh*2+u)*64+w)*2 + half, half8 = ch u*16+half*8+j
    int t = (bid - 8192) * 256 + threadIdx.x;    // 0..262143
    int half = t & 1;
    int w    = (t >> 1) & 63;
    int u    = (t >> 7) & 1;
    int bh   = t >> 8;
    const float* xp = x + (size_t)(bh >> 6) * 131072 + (u * 16 + half * 8) * 4096 +
                      (bh & 63) * 64 + w;
    half8 v;
#pragma unroll
    for (int j = 0; j < 8; ++j) v[j] = (_Float16)fmaxf(xp[j * 4096], 0.0f);
    ws[NBF + NBAS + t] = v;
  } else {
    int t = (bid - 9216) * 256 + threadIdx.x;    // 0..20735
    half8 v;
    int dst;
    if (t < NOUT * FIN) {                   // spline (o,f) pairs
      int o = t / FIN;
      int f = t - o * FIN;
      float scale = sc[t];
      const float* p = sw + t * 8;
#pragma unroll
      for (int j = 0; j < 8; ++j) v[j] = (_Float16)(p[j] * scale);
      int c  = f / 9;
      int r  = f - c * 9;
      int ii = r / 3;
      int jj = r - ii * 3;
      int pp = ii * 3 + jj;
      int u  = c >> 1, half = c & 1;
      int nf = o >> 5, col = o & 31;
      dst = pp * 2048 + u * 128 + nf * 64 + half * 32 + col;
    } else {                                // base frags: dst = 18432 + t2
      int t2 = t - NOUT * FIN;              // 0..2303
      int lane = t2 & 63;
      int nf   = (t2 >> 6) & 1;
      int u    = (t2 >> 7) & 1;
      int pos  = t2 >> 8;                   // 0..8
      int half = lane >> 5, col = lane & 31;
      int o = nf * 32 + col;
#pragma unroll
      for (int j = 0; j < 8; ++j)
        v[j] = (_Float16)bw[o * FIN + 9 * (u * 16 + half * 8 + j) + pos];
      dst = NOUT * FIN + t2;
    }
    ws[dst] = v;
  }
}

// ---- main: 32x32x16; block = 4 rows x 2 K (8 waves), N=32 via block nh ----
#define MFMA32(A, B, C) __builtin_amdgcn_mfma_f32_32x32x16_f16((A), (B), (C), 0, 0, 0)

#define LOAD_AF(PP, AF)                                                     \
  {                                                                         \
    const half8* pAf_ = bbS + ((PP) / 3) * 2048 + ((PP) % 3) * 2;           \
    _Pragma("unroll")                                                       \
    for (int uu = 0; uu < 8; ++uu) {                                        \
      AF[uu * 2]     = pAf_[(ulo + uu) * 128];                              \
      AF[uu * 2 + 1] = pAf_[(ulo + uu) * 128 + 64];                         \
    }                                                                       \
  }

// stage only this block's nh half of the pair: 1024 half8 = 16 KB
#define PAIR(PP, AFC, AFN)                                                  \
  {                                                                         \
    half8 stg[2];                                                           \
    if ((PP) < 8) {                                                         \
      const half8* src_ = bfrag + ((PP) + 1) * 2048 + nhoff;                \
      _Pragma("unroll")                                                     \
      for (int i = 0; i < 2; ++i) {                                         \
        int idx_ = i * 512 + tid;                                           \
        stg[i] = src_[(idx_ >> 6) * 128 + (idx_ & 63)];                     \
      }                                                                     \
      LOAD_AF((PP) + 1, AFN)                                                \
    }                                                                       \
    _Pragma("unroll")                                                       \
    for (int uu = 0; uu < 8; ++uu) {                                        \
      int u_ = ulo + uu;                                                    \
      half8 bf_ = bcur[u_ * 64 + lane];                                     \
      acc[0] = MFMA32(AFC[uu * 2], bf_, acc[0]);                            \
      acc[1] = MFMA32(AFC[uu * 2 + 1], bf_, acc[1]);                        \
    }                                                                       \
    if ((PP) < 8) {                                                         \
      _Pragma("unroll")                                                     \
      for (int i = 0; i < 2; ++i) balt[i * 512 + tid] = stg[i];             \
    }                                                                       \
    __syncthreads();                                                        \
    { half8* t_ = bcur; bcur = balt; balt = t_; }                           \
  }

#define BASE_LOAD(POS, A0, A1, B0)                                          \
  {                                                                         \
    constexpr int i2_ = (POS) / 3, j2_ = (POS) - 3 * ((POS) / 3);           \
    const half8* pAf_ = xr + (size_t)((b * 64 + hoc + i2_) * 2 + g2) * 128 + \
                        j2_ * 2 + laneoff;                                  \
    A0 = pAf_[0];                                                           \
    A1 = pAf_[64];                                                          \
    B0 = bfrag[NOUT * FIN + ((POS) * 2 + g2) * 128 + nhoff + lane];         \
  }

#define BASE_MMA(A0, A1, B0)                                                \
  {                                                                         \
    acc[0] = MFMA32(A0, B0, acc[0]);                                        \
    acc[1] = MFMA32(A1, B0, acc[1]);                                        \
  }

__global__ __launch_bounds__(512, 4) void kan_main(
    const half8* __restrict__ ws,
    float* __restrict__ out) {
  __shared__ __align__(16) unsigned char ldsraw[65536];
  half8* lbf0 = (half8*)ldsraw;             // [1024] = 16 KB (pair buffer A)
  half8* lbf1 = (half8*)(ldsraw + 16384);   // pair buffer B
  float* red  = (float*)(ldsraw + 32768);   // 8192 floats = 32 KB (reduce)

  const half8* __restrict__ bfrag = ws;
  const half8* __restrict__ bas   = ws + NBF;
  const half8* __restrict__ xr    = ws + NBF + NBAS;

  const int tid = threadIdx.x;
  int bid0 = blockIdx.x;                // 0..511
  // nh in the HIGH bit: blocks c and c+256 round-robin to the same CU and
  // are the two N-halves of the same (b,hg) -> af fetches shared in L1/L2.
  const int nh    = bid0 >> 8;          // 0..1
  int inner = bid0 & 255;
  // XCD swizzle on inner: 256 = 8*32, bijective
  int bidS = (inner & 7) * 32 + (inner >> 3);
  const int b  = bidS >> 4;             // 0..15
  const int hg = bidS & 15;             // 0..15

  const int lane = tid & 63;
  const int wv   = tid >> 6;            // 0..7
  const int g2   = wv >> 2;             // K half
  const int rw   = wv & 3;              // row within block (0..3)
  const int l31  = lane & 31;
  const int lhi  = lane >> 5;
  const int laneoff = l31 * 2 + lhi;    // af lane permutation (1KB contiguous)
  const int nhoff = nh * 64;
  const int ho   = hg * 4 + rw;         // 0..63; rows 62,63 garbage (not stored)
  const int hoc  = ho < 61 ? ho : 61;
  const int ulo  = g2 * 8;              // spline u range [ulo, ulo+8)

  f32x16 acc[2];
#pragma unroll
  for (int mt = 0; mt < 2; ++mt)
#pragma unroll
    for (int e = 0; e < 16; ++e) acc[mt][e] = 0.f;

  const half8* bbS = bas + (size_t)(b * 64 + hoc) * 2048 + laneoff;

  half8 afA[16], afB[16];

  // ---- prologue: stage pair 0 bf (nh half) + load pair 0 af ----
#pragma unroll
  for (int i = 0; i < 2; ++i) {
    int idx = i * 512 + tid;
    lbf0[idx] = bfrag[(idx >> 6) * 128 + nhoff + (idx & 63)];
  }
  LOAD_AF(0, afA)
  __syncthreads();
  half8* bcur = lbf0;
  half8* balt = lbf1;

  half8 bx0, bx1, bxb;                  // base prefetch set X
  half8 by0, by1, byb;                  // base prefetch set Y

  // ---- spline pairs, fully unrolled with alternating af register sets ----
  PAIR(0, afA, afB)
  PAIR(1, afB, afA)
  PAIR(2, afA, afB)
  PAIR(3, afB, afA)
  PAIR(4, afA, afB)
  PAIR(5, afB, afA)
  PAIR(6, afA, afB)
  PAIR(7, afB, afA)
  BASE_LOAD(0, bx0, bx1, bxb)           // overlap base pos-0 loads w/ last pair
  PAIR(8, afA, afB)

  // ---- base K-slices (u = g2): 1-ahead prefetch, alternating X/Y sets ----
  BASE_LOAD(1, by0, by1, byb)
  BASE_MMA(bx0, bx1, bxb)
  BASE_LOAD(2, bx0, bx1, bxb)
  BASE_MMA(by0, by1, byb)
  BASE_LOAD(3, by0, by1, byb)
  BASE_MMA(bx0, bx1, bxb)
  BASE_LOAD(4, bx0, bx1, bxb)
  BASE_MMA(by0, by1, byb)
  BASE_LOAD(5, by0, by1, byb)
  BASE_MMA(bx0, bx1, bxb)
  BASE_LOAD(6, bx0, bx1, bxb)
  BASE_MMA(by0, by1, byb)
  BASE_LOAD(7, by0, by1, byb)
  BASE_MMA(bx0, bx1, bxb)
  BASE_LOAD(8, bx0, bx1, bxb)
  BASE_MMA(by0, by1, byb)
  BASE_MMA(bx0, bx1, bxb)

  // ---- K-split reduce (g2=1 -> g2=0) via red (32 KB); rotated chunks ----
  if (g2) {
    int base = (rw * 64 + lane) * 32;
#pragma unroll
    for (int mt = 0; mt < 2; ++mt)
#pragma unroll
      for (int q4 = 0; q4 < 4; ++q4) {
        int pos = ((mt * 4 + q4) + lane) & 7;
        f32x4 ch = {acc[mt][q4 * 4], acc[mt][q4 * 4 + 1],
                    acc[mt][q4 * 4 + 2], acc[mt][q4 * 4 + 3]};
        *(f32x4*)&red[base + pos * 4] = ch;
      }
  }
  __syncthreads();

  if (!g2) {
    int base = (rw * 64 + lane) * 32;
#pragma unroll
    for (int mt = 0; mt < 2; ++mt)
#pragma unroll
      for (int q4 = 0; q4 < 4; ++q4) {
        int pos = ((mt * 4 + q4) + lane) & 7;
        f32x4 ch = *(const f32x4*)&red[base + pos * 4];
        acc[mt][q4 * 4]     += ch[0];
        acc[mt][q4 * 4 + 1] += ch[1];
        acc[mt][q4 * 4 + 2] += ch[2];
        acc[mt][q4 * 4 + 3] += ch[3];
      }

    // ---- epilogue: col(=out)=nh*32+l31, row(=px w)=mt*32+(reg&3)+8*(reg>>2)+4*lhi
    if (ho < 62) {
      float* ob = out + b * (NOUT * LPB) + ho * 62;
      const int o = nh * 32 + l31;
#pragma unroll
      for (int mt = 0; mt < 2; ++mt) {
#pragma unroll
        for (int reg = 0; reg < 16; ++reg) {
          int wo2 = mt * 32 + (reg & 3) + 8 * (reg >> 2) + 4 * lhi;
          if (wo2 < 62) {
            ob[o * LPB + wo2] = acc[mt][reg];
          }
        }
      }
    }
  }
}

// ================= legacy fallback (round-0 verified, verbatim) =================
#define KSPL 72
__global__ void prep_bfrag_legacy(const float* __restrict__ bw,
                                  const float* __restrict__ sw,
                                  const float* __restrict__ sc,
                                  half8* __restrict__ bfrag) {
  int t = blockIdx.x * 256 + threadIdx.x;
  half8 v;
  int dst;
  if (t < NOUT * FIN) {
    int o = t / FIN;
    int f = t - o * FIN;
    float scale = sc[t];
    const float* p = sw + t * 8;
#pragma unroll
    for (int c = 0; c < 8; ++c) v[c] = (_Float16)(p[c] * scale);
    int ch = f / 9;
    int r  = f - ch * 9;
    int ii = r / 3;
    int jj = r - ii * 3;
    int g  = ch >> 2, q = ch & 3;
    int kt = ii * 24 + jj * 8 + g;
    dst = (kt * 4 + (o >> 4)) * 64 + q * 16 + (o & 15);
  } else {
    int t2 = t - NOUT * FIN;
    int lane = t2 & 63;
    int nf = (t2 >> 6) & 3;
    int ktb = t2 >> 8;
    int o = nf * 16 + (lane & 15);
    int f0 = ktb * 32 + (lane >> 4) * 8;
    const float* p = bw + o * FIN + f0;
#pragma unroll
    for (int c = 0; c < 8; ++c) v[c] = (_Float16)p[c];
    dst = ((KSPL + ktb) * 4 + nf) * 64 + lane;
  }
  bfrag[dst] = v;
}

__global__ __launch_bounds__(256, 4) void kan_main_legacy(
    const float* __restrict__ x,
    const half8* __restrict__ bfrag,
    float* __restrict__ out) {
  __shared__ float lx[LDSL];
  const int tid = threadIdx.x;
  const int bid = blockIdx.x;
  const int b  = bid / 62;
  const int ho = bid - b * 62;
  const float* xb = x + b * 131072 + ho * 64;
#pragma unroll
  for (int r = 0; r < 6; ++r) {
    int gid = r * 256 + tid;
    int row = gid >> 4;
    int c   = (row * 683) >> 11;
    int ii  = row - c * 3;
    int colv = (gid & 15) * 4;
    const float4 v = *(const float4*)(xb + c * 4096 + ii * 64 + colv);
    *(float4*)(&lx[c * SCL + ii * 64 + colv]) = v;
  }
  __syncthreads();
  const int lane = tid & 63;
  const int wv   = tid >> 6;
  const int quad = lane >> 4;
  const int m16  = lane & 15;
  const int wo   = wv * 16 + m16;
  f32x4 acc[4];
#pragma unroll
  for (int nf = 0; nf < 4; ++nf) acc[nf] = (f32x4){0.f, 0.f, 0.f, 0.f};
  int kt = 0;
#pragma unroll
  for (int ii = 0; ii < 3; ++ii) {
#pragma unroll
    for (int jj = 0; jj < 3; ++jj) {
      const float* lbase = lx + quad * SCL + ii * 64 + wo + jj;
#pragma unroll
      for (int g = 0; g < 8; ++g) {
        float xv = lbase[g * (4 * SCL)];
        half8 af = bspline8(xv);
#pragma unroll
        for (int nf = 0; nf < 4; ++nf) {
          half8 bf = bfrag[(kt * 4 + nf) * 64 + lane];
          acc[nf] = __builtin_amdgcn_mfma_f32_16x16x32_f16(af, bf, acc[nf], 0, 0, 0);
        }
        ++kt;
      }
    }
  }
#pragma unroll
  for (int kb = 0; kb < 9; ++kb) {
    int f0 = kb * 32 + quad * 8;
    half8 a;
#pragma unroll
    for (int j = 0; j < 8; ++j) {
      int f = f0 + j;
      int c = (f * 57) >> 9;
      int r = f - c * 9;
      int i2 = (r * 11) >> 5;
      int j2 = r - i2 * 3;
      a[j] = (_Float16)fmaxf(lx[c * SCL + i2 * 64 + wo + j2], 0.0f);
    }
#pragma unroll
    for (int nf = 0; nf < 4; ++nf) {
      half8 bf = bfrag[((KSPL + kb) * 4 + nf) * 64 + lane];
      acc[nf] = __builtin_amdgcn_mfma_f32_16x16x32_f16(a, bf, acc[nf], 0, 0, 0);
    }
  }
  float* ob = out + b * (NOUT * LPB) + ho * 62;
#pragma unroll
  for (int rg = 0; rg < 4; ++rg) {
    int wo2 = wv * 16 + quad * 4 + rg;
    if (wo2 < 62) {
#pragma unroll
      for (int nf = 0; nf < 4; ++nf) {
        int o = nf * 16 + m16;
        ob[o * LPB + wo2] = acc[nf][rg];
      }
    }
  }
}

extern "C" void kernel_launch(void* const* d_in, const int* in_sizes, int n_in,
                              void* d_out, int out_size, void* d_ws, size_t ws_size,
                              hipStream_t stream) {
  const float* x  = (const float*)d_in[0];
  const float* bw = (const float*)d_in[1];  // (64, 288)
  const float* sw = (const float*)d_in[2];  // (64, 288, 8)
  const float* sc = (const float*)d_in[3];  // (64, 288)
  float* out = (float*)d_out;
  half8* ws = (half8*)d_ws;

  const size_t need = (size_t)(NBF + NBAS + NXR + PADS) * sizeof(half8);  // ~38.1 MB
  if (ws_size >= need) {
    prep_all<<<9297, 256, 0, stream>>>(x, bw, sw, sc, ws);
    kan_main<<<512, 512, 0, stream>>>(ws, out);
  } else {
    prep_bfrag_legacy<<<81, 256, 0, stream>>>(bw, sw, sc, ws);
    kan_main_legacy<<<16 * 62, 256, 0, stream>>>(x, ws, out);
  }
}

// Round 14
// 121.438 us; speedup vs baseline: 1.2623x; 1.2623x over previous
//
#include <hip/hip_runtime.h>
#include <stdint.h>

typedef _Float16 half8  __attribute__((ext_vector_type(8)));
typedef float    f32x4  __attribute__((ext_vector_type(4)));
typedef float    f32x16 __attribute__((ext_vector_type(16)));
typedef uint32_t u32x4  __attribute__((ext_vector_type(4)));

#define FIN  288
#define NOUT 64
#define LPB  3844            // 62*62
#define NBF  20736           // bfrag half8 slots (331,776 B)
#define NBAS (16*64*16*64*2) // basis half8 slots (33.5 MB), [b][h][u16][w64][half2]
#define NXR  (16*64*2*64*2)  // relu(x) half8 slots (4.2 MB), [b][h][u2][w64][half2]
#define PADS 16              // OOB-read pad

// legacy LDS (fallback path, byte-identical to the round-0 verified kernel)
#define SCL  200
#define LDSL (31*SCL + 2*64 + 64 + 8)

// R11/R12/R13 counters: dur == (FETCH+WRITE)/~3.5 TB/s in every config; the
// dominant term is basis x3 jj re-reads (pairs 3ii+jj are ~7us apart ->
// L2 evicted). FIX: jj INNERMOST — for fixed (ii,u) the 3 jj af windows are
// the same ~1KB +-32B, L1-served; each basis row streams ONCE per block.
// bf (331KB, L2-resident) read direct from global -> NO LDS staging, NO
// barriers in the main loop. Shape/geometry/reduce/epilogue = verified R12.

// ---------------- cubic B-spline basis: 8 slots, f16-packed ----------------
__device__ inline half8 bspline8(float xv) {
  float u = fmaf(xv, 2.5f, 5.5f);
  float fi = floorf(u);
  int i = (int)fi;
  float t = u - fi, s = 1.0f - t;
  float t2 = t * t, t3 = t2 * t;
  float s2 = s * s, s3 = s2 * s;
  float w3 = t3 * 0.16666667f;
  float w0 = s3 * 0.16666667f;
  float w1 = fmaf(0.5f, t3, -t2) + 0.66666667f;
  float w2 = fmaf(0.5f, s3, -s2) + 0.66666667f;
  uint32_t u01 = __builtin_bit_cast(uint32_t, __builtin_amdgcn_cvt_pkrtz(w0, w1));
  uint32_t u23 = __builtin_bit_cast(uint32_t, __builtin_amdgcn_cvt_pkrtz(w2, w3));
  uint64_t V = (uint64_t)u01 | ((uint64_t)u23 << 32);
  uint32_t vl = (uint32_t)(V << 16);
  u32x4 fr;
#pragma unroll
  for (int q = 0; q < 4; ++q) {
    int d = i - 2 * q;
    uint32_t rr = (uint32_t)(V >> ((48 - 16 * d) & 63));
    fr[q] = ((uint32_t)d <= 3u) ? rr : ((d == 4) ? vl : 0u);
  }
  return __builtin_bit_cast(half8, fr);
}

// -------- prep: basis + relu(x) f16 + weight B-fragments, all in ws --------
__global__ __launch_bounds__(256) void prep_all(const float* __restrict__ x,
                                                const float* __restrict__ bw,
                                                const float* __restrict__ sw,
                                                const float* __restrict__ sc,
                                                half8* __restrict__ ws) {
  int bid = blockIdx.x;
  if (bid < 8192) {
    // basis: thread t writes slot t (coalesced stores)
    int t = bid * 256 + threadIdx.x;        // 0..2097151
    int half = t & 1;
    int w    = (t >> 1) & 63;
    int u    = (t >> 7) & 15;
    int bh   = t >> 11;                     // b*64 + h
    float xv = x[(size_t)(bh >> 6) * 131072 + (u * 2 + half) * 4096 +
                 (bh & 63) * 64 + w];
    ws[NBF + t] = bspline8(xv);
  } else if (bid < 9216) {
    // relu(x) -> f16: slot ((bh*2+u)*64+w)*2 + half, half8 = ch u*16+half*8+j
    int t = (bid - 8192) * 256 + threadIdx.x;    // 0..262143
    int half = t & 1;
    int w    = (t >> 1) & 63;
    int u    = (t >> 7) & 1;
    int bh   = t >> 8;
    const float* xp = x + (size_t)(bh >> 6) * 131072 + (u * 16 + half * 8) * 4096 +
                      (bh & 63) * 64 + w;
    half8 v;
#pragma unroll
    for (int j = 0; j < 8; ++j) v[j] = (_Float16)fmaxf(xp[j * 4096], 0.0f);
    ws[NBF + NBAS + t] = v;
  } else {
    int t = (bid - 9216) * 256 + threadIdx.x;    // 0..20735
    half8 v;
    int dst;
    if (t < NOUT * FIN) {                   // spline (o,f) pairs
      int o = t / FIN;
      int f = t - o * FIN;
      float scale = sc[t];
      const float* p = sw + t * 8;
#pragma unroll
      for (int j = 0; j < 8; ++j) v[j] = (_Float16)(p[j] * scale);
      int c  = f / 9;
      int r  = f - c * 9;
      int ii = r / 3;
      int jj = r - ii * 3;
      int pp = ii * 3 + jj;
      int u  = c >> 1, half = c & 1;
      int nf = o >> 5, col = o & 31;
      dst = pp * 2048 + u * 128 + nf * 64 + half * 32 + col;
    } else {                                // base frags: dst = 18432 + t2
      int t2 = t - NOUT * FIN;              // 0..2303
      int lane = t2 & 63;
      int nf   = (t2 >> 6) & 1;
      int u    = (t2 >> 7) & 1;
      int pos  = t2 >> 8;                   // 0..8
      int half = lane >> 5, col = lane & 31;
      int o = nf * 32 + col;
#pragma unroll
      for (int j = 0; j < 8; ++j)
        v[j] = (_Float16)bw[o * FIN + 9 * (u * 16 + half * 8 + j) + pos];
      dst = NOUT * FIN + t2;
    }
    ws[dst] = v;
  }
}

// ---- main: 32x32x16; 16 waves = nh x g2 x 4 rw; jj-innermost; no staging ----
#define MFMA32(A, B, C) __builtin_amdgcn_mfma_f32_32x32x16_f16((A), (B), (C), 0, 0, 0)

#define BASE_LOAD(POS, A0, A1, B0)                                          \
  {                                                                         \
    constexpr int i2_ = (POS) / 3, j2_ = (POS) - 3 * ((POS) / 3);           \
    const half8* pAf_ = xr + (size_t)((b * 64 + hoc + i2_) * 2 + g2) * 128 + \
                        j2_ * 2 + laneoff;                                  \
    A0 = pAf_[0];                                                           \
    A1 = pAf_[64];                                                          \
    B0 = bfrag[NOUT * FIN + ((POS) * 2 + g2) * 128 + nhoff + lane];         \
  }

#define BASE_MMA(A0, A1, B0)                                                \
  {                                                                         \
    acc[0] = MFMA32(A0, B0, acc[0]);                                        \
    acc[1] = MFMA32(A1, B0, acc[1]);                                        \
  }

__global__ __launch_bounds__(1024, 4) void kan_main(
    const half8* __restrict__ ws,
    float* __restrict__ out) {
  __shared__ float red[16384];              // 64 KB (reduce only)

  const half8* __restrict__ bfrag = ws;
  const half8* __restrict__ bas   = ws + NBF;
  const half8* __restrict__ xr    = ws + NBF + NBAS;

  const int tid = threadIdx.x;
  int bid0 = blockIdx.x;                // 0..255
  // XCD swizzle: 256 = 8*32, bijective; consecutive hg land on one XCD
  int bid = (bid0 & 7) * 32 + (bid0 >> 3);
  const int b  = bid >> 4;              // 0..15
  const int hg = bid & 15;              // 0..15

  const int lane = tid & 63;
  const int wv   = tid >> 6;            // 0..15
  const int nh   = wv & 1;              // N half (output cols nh*32..)
  const int g2   = (wv >> 1) & 1;       // K half
  const int rw   = wv >> 2;             // row within block (0..3)
  const int l31  = lane & 31;
  const int lhi  = lane >> 5;
  const int laneoff = l31 * 2 + lhi;    // af lane permutation (1KB contiguous)
  const int nhoff = nh * 64;
  const int ho   = hg * 4 + rw;         // 0..63; rows 62,63 garbage (not stored)
  const int hoc  = ho < 61 ? ho : 61;
  const int ulo  = g2 * 8;              // spline u range [ulo, ulo+8)

  f32x16 acc[2];
#pragma unroll
  for (int mt = 0; mt < 2; ++mt)
#pragma unroll
    for (int e = 0; e < 16; ++e) acc[mt][e] = 0.f;

  const half8* bbS = bas + (size_t)(b * 64 + hoc) * 2048 + laneoff;

  // ---- spline: ii -> u -> jj (jj re-reads are L1-resident, row streams 1x) ----
#pragma unroll
  for (int ii = 0; ii < 3; ++ii) {
#pragma unroll
    for (int u8 = 0; u8 < 8; ++u8) {
      const int u = ulo + u8;
      half8 af[6];
      half8 bf[3];
#pragma unroll
      for (int jj = 0; jj < 3; ++jj) {
        const half8* pA = bbS + ii * 2048 + jj * 2 + u * 128;
        af[jj * 2]     = pA[0];
        af[jj * 2 + 1] = pA[64];
        bf[jj] = bfrag[(ii * 3 + jj) * 2048 + u * 128 + nhoff + lane];
      }
#pragma unroll
      for (int jj = 0; jj < 3; ++jj) {
        acc[0] = MFMA32(af[jj * 2],     bf[jj], acc[0]);
        acc[1] = MFMA32(af[jj * 2 + 1], bf[jj], acc[1]);
      }
    }
  }

  // ---- base K-slices (u = g2): 1-ahead prefetch, alternating X/Y sets ----
  half8 bx0, bx1, bxb;
  half8 by0, by1, byb;
  BASE_LOAD(0, bx0, bx1, bxb)
  BASE_LOAD(1, by0, by1, byb)
  BASE_MMA(bx0, bx1, bxb)
  BASE_LOAD(2, bx0, bx1, bxb)
  BASE_MMA(by0, by1, byb)
  BASE_LOAD(3, by0, by1, byb)
  BASE_MMA(bx0, bx1, bxb)
  BASE_LOAD(4, bx0, bx1, bxb)
  BASE_MMA(by0, by1, byb)
  BASE_LOAD(5, by0, by1, byb)
  BASE_MMA(bx0, bx1, bxb)
  BASE_LOAD(6, bx0, bx1, bxb)
  BASE_MMA(by0, by1, byb)
  BASE_LOAD(7, by0, by1, byb)
  BASE_MMA(bx0, bx1, bxb)
  BASE_LOAD(8, bx0, bx1, bxb)
  BASE_MMA(by0, by1, byb)
  BASE_MMA(bx0, bx1, bxb)

  // ---- K-split reduce (g2=1 -> g2=0) via red (64 KB); rotated chunks ----
  if (g2) {
    int base = ((rw * 2 + nh) * 64 + lane) * 32;
#pragma unroll
    for (int mt = 0; mt < 2; ++mt)
#pragma unroll
      for (int q4 = 0; q4 < 4; ++q4) {
        int pos = ((mt * 4 + q4) + lane) & 7;
        f32x4 ch = {acc[mt][q4 * 4], acc[mt][q4 * 4 + 1],
                    acc[mt][q4 * 4 + 2], acc[mt][q4 * 4 + 3]};
        *(f32x4*)&red[base + pos * 4] = ch;
      }
  }
  __syncthreads();

  if (!g2) {
    int base = ((rw * 2 + nh) * 64 + lane) * 32;
#pragma unroll
    for (int mt = 0; mt < 2; ++mt)
#pragma unroll
      for (int q4 = 0; q4 < 4; ++q4) {
        int pos = ((mt * 4 + q4) + lane) & 7;
        f32x4 ch = *(const f32x4*)&red[base + pos * 4];
        acc[mt][q4 * 4]     += ch[0];
        acc[mt][q4 * 4 + 1] += ch[1];
        acc[mt][q4 * 4 + 2] += ch[2];
        acc[mt][q4 * 4 + 3] += ch[3];
      }

    // ---- epilogue: col(=out)=nh*32+l31, row(=px w)=mt*32+(reg&3)+8*(reg>>2)+4*lhi
    if (ho < 62) {
      float* ob = out + b * (NOUT * LPB) + ho * 62;
      const int o = nh * 32 + l31;
#pragma unroll
      for (int mt = 0; mt < 2; ++mt) {
#pragma unroll
        for (int reg = 0; reg < 16; ++reg) {
          int wo2 = mt * 32 + (reg & 3) + 8 * (reg >> 2) + 4 * lhi;
          if (wo2 < 62) {
            ob[o * LPB + wo2] = acc[mt][reg];
          }
        }
      }
    }
  }
}

// ================= legacy fallback (round-0 verified, verbatim) =================
#define KSPL 72
__global__ void prep_bfrag_legacy(const float* __restrict__ bw,
                                  const float* __restrict__ sw,
                                  const float* __restrict__ sc,
                                  half8* __restrict__ bfrag) {
  int t = blockIdx.x * 256 + threadIdx.x;
  half8 v;
  int dst;
  if (t < NOUT * FIN) {
    int o = t / FIN;
    int f = t - o * FIN;
    float scale = sc[t];
    const float* p = sw + t * 8;
#pragma unroll
    for (int c = 0; c < 8; ++c) v[c] = (_Float16)(p[c] * scale);
    int ch = f / 9;
    int r  = f - ch * 9;
    int ii = r / 3;
    int jj = r - ii * 3;
    int g  = ch >> 2, q = ch & 3;
    int kt = ii * 24 + jj * 8 + g;
    dst = (kt * 4 + (o >> 4)) * 64 + q * 16 + (o & 15);
  } else {
    int t2 = t - NOUT * FIN;
    int lane = t2 & 63;
    int nf = (t2 >> 6) & 3;
    int ktb = t2 >> 8;
    int o = nf * 16 + (lane & 15);
    int f0 = ktb * 32 + (lane >> 4) * 8;
    const float* p = bw + o * FIN + f0;
#pragma unroll
    for (int c = 0; c < 8; ++c) v[c] = (_Float16)p[c];
    dst = ((KSPL + ktb) * 4 + nf) * 64 + lane;
  }
  bfrag[dst] = v;
}

__global__ __launch_bounds__(256, 4) void kan_main_legacy(
    const float* __restrict__ x,
    const half8* __restrict__ bfrag,
    float* __restrict__ out) {
  __shared__ float lx[LDSL];
  const int tid = threadIdx.x;
  const int bid = blockIdx.x;
  const int b  = bid / 62;
  const int ho = bid - b * 62;
  const float* xb = x + b * 131072 + ho * 64;
#pragma unroll
  for (int r = 0; r < 6; ++r) {
    int gid = r * 256 + tid;
    int row = gid >> 4;
    int c   = (row * 683) >> 11;
    int ii  = row - c * 3;
    int colv = (gid & 15) * 4;
    const float4 v = *(const float4*)(xb + c * 4096 + ii * 64 + colv);
    *(float4*)(&lx[c * SCL + ii * 64 + colv]) = v;
  }
  __syncthreads();
  const int lane = tid & 63;
  const int wv   = tid >> 6;
  const int quad = lane >> 4;
  const int m16  = lane & 15;
  const int wo   = wv * 16 + m16;
  f32x4 acc[4];
#pragma unroll
  for (int nf = 0; nf < 4; ++nf) acc[nf] = (f32x4){0.f, 0.f, 0.f, 0.f};
  int kt = 0;
#pragma unroll
  for (int ii = 0; ii < 3; ++ii) {
#pragma unroll
    for (int jj = 0; jj < 3; ++jj) {
      const float* lbase = lx + quad * SCL + ii * 64 + wo + jj;
#pragma unroll
      for (int g = 0; g < 8; ++g) {
        float xv = lbase[g * (4 * SCL)];
        half8 af = bspline8(xv);
#pragma unroll
        for (int nf = 0; nf < 4; ++nf) {
          half8 bf = bfrag[(kt * 4 + nf) * 64 + lane];
          acc[nf] = __builtin_amdgcn_mfma_f32_16x16x32_f16(af, bf, acc[nf], 0, 0, 0);
        }
        ++kt;
      }
    }
  }
#pragma unroll
  for (int kb = 0; kb < 9; ++kb) {
    int f0 = kb * 32 + quad * 8;
    half8 a;
#pragma unroll
    for (int j = 0; j < 8; ++j) {
      int f = f0 + j;
      int c = (f * 57) >> 9;
      int r = f - c * 9;
      int i2 = (r * 11) >> 5;
      int j2 = r - i2 * 3;
      a[j] = (_Float16)fmaxf(lx[c * SCL + i2 * 64 + wo + j2], 0.0f);
    }
#pragma unroll
    for (int nf = 0; nf < 4; ++nf) {
      half8 bf = bfrag[((KSPL + kb) * 4 + nf) * 64 + lane];
      acc[nf] = __builtin_amdgcn_mfma_f32_16x16x32_f16(a, bf, acc[nf], 0, 0, 0);
    }
  }
  float* ob = out + b * (NOUT * LPB) + ho * 62;
#pragma unroll
  for (int rg = 0; rg < 4; ++rg) {
    int wo2 = wv * 16 + quad * 4 + rg;
    if (wo2 < 62) {
#pragma unroll
      for (int nf = 0; nf < 4; ++nf) {
        int o = nf * 16 + m16;
        ob[o * LPB + wo2] = acc[nf][rg];
      }
    }
  }
}

extern "C" void kernel_launch(void* const* d_in, const int* in_sizes, int n_in,
                              void* d_out, int out_size, void* d_ws, size_t ws_size,
                              hipStream_t stream) {
  const float* x  = (const float*)d_in[0];
  const float* bw = (const float*)d_in[1];  // (64, 288)
  const float* sw = (const float*)d_in[2];  // (64, 288, 8)
  const float* sc = (const float*)d_in[3];  // (64, 288)
  float* out = (float*)d_out;
  half8* ws = (half8*)d_ws;

  const size_t need = (size_t)(NBF + NBAS + NXR + PADS) * sizeof(half8);  // ~38.1 MB
  if (ws_size >= need) {
    prep_all<<<9297, 256, 0, stream>>>(x, bw, sw, sc, ws);
    kan_main<<<256, 1024, 0, stream>>>(ws, out);
  } else {
    prep_bfrag_legacy<<<81, 256, 0, stream>>>(bw, sw, sc, ws);
    kan_main_legacy<<<16 * 62, 256, 0, stream>>>(x, ws, out);
  }
}